// Round 1
// baseline (4802.346 us; speedup 1.0000x reference)
//
#include <hip/hip_runtime.h>
#include <hip/hip_bf16.h>
#include <stdint.h>

// LSTMModelLite: B=128,T=512,F=784,H=256,C=10
// Pipeline:
//   repack_w   : kernel[784][1024] fp32 -> Wt_hi/Wt_lo bf16 [1024][800] (transposed, K padded)
//   repack_wr  : rec_kernel[256][1024] fp32 -> Wrp uint32 [128][1024] (k-pair packed bf16)
//   gemm_xw    : xw = x @ kernel, bf16 MFMA (W split hi+lo for accuracy), xw stored bf16
//   scan_kernel: 128 WGs (1/batch), 512 sequential steps, fused BN+tanh+FC epilogue
// ws layout: xw 134217728 B | wt_hi 1638400 | wt_lo 1638400 | wrp 524288  (~138 MB)

typedef __attribute__((ext_vector_type(8))) short short8;
typedef __attribute__((ext_vector_type(4))) float f32x4;

__device__ __forceinline__ unsigned short f2bf(float f) {
  union { float f; uint32_t u; } v; v.f = f;
  return (unsigned short)((v.u + 0x7fffu + ((v.u >> 16) & 1u)) >> 16);
}
__device__ __forceinline__ float bfu2f(uint32_t u16) {
  union { uint32_t u; float f; } v; v.u = u16 << 16; return v.f;
}
__device__ __forceinline__ float bflo(uint32_t u) {
  union { uint32_t u; float f; } v; v.u = u << 16; return v.f;
}
__device__ __forceinline__ float bfhi(uint32_t u) {
  union { uint32_t u; float f; } v; v.u = u & 0xffff0000u; return v.f;
}
__device__ __forceinline__ float sigm(float x) { return 1.f / (1.f + __expf(-x)); }
__device__ __forceinline__ float tanh_(float x) {
  float e = __expf(2.f * x);
  return 1.f - 2.f / (e + 1.f);
}

__global__ void repack_w(const float* __restrict__ w, unsigned short* __restrict__ wt_hi,
                         unsigned short* __restrict__ wt_lo) {
  int idx = blockIdx.x * 256 + threadIdx.x;  // n*800 + k
  if (idx >= 1024 * 800) return;
  int n = idx / 800, k = idx - n * 800;
  float v = (k < 784) ? w[k * 1024 + n] : 0.f;
  unsigned short hi = f2bf(v);
  wt_hi[idx] = hi;
  wt_lo[idx] = f2bf(v - bfu2f(hi));
}

__global__ void repack_wr(const float* __restrict__ rk, uint32_t* __restrict__ wrp) {
  int idx = blockIdx.x * 256 + threadIdx.x;  // kp*1024 + n
  if (idx >= 128 * 1024) return;
  int kp = idx >> 10, n = idx & 1023;
  uint32_t lo = f2bf(rk[(2 * kp) * 1024 + n]);
  uint32_t hi = f2bf(rk[(2 * kp + 1) * 1024 + n]);
  wrp[idx] = lo | (hi << 16);
}

// ---- xw = x @ kernel ; BM=BN=128, BK=32, 256 thr, B split hi+lo (2 MFMAs) ----
__global__ __launch_bounds__(256, 2) void gemm_xw(
    const float* __restrict__ x, const unsigned short* __restrict__ wt_hi,
    const unsigned short* __restrict__ wt_lo, unsigned short* __restrict__ xw) {
  __shared__ __align__(16) unsigned short As[128][40];  // [m][k], pad 32->40 (bank-safe)
  __shared__ __align__(16) unsigned short Bh[128][40];  // [n][k]
  __shared__ __align__(16) unsigned short Bl[128][40];
  const int tid = threadIdx.x;
  const int m0 = blockIdx.y << 7;
  const int n0 = blockIdx.x << 7;
  const int lane = tid & 63, wv = tid >> 6;
  const int wr = wv >> 1, wc = wv & 1;       // 2x2 wave quadrants of 64x64
  const int fm = lane & 15;
  const int fkb = (lane >> 4) << 3;          // frag k base: 0,8,16,24
  const int sr = tid >> 1, sh = (tid & 1) << 4;  // staging: row, 16-elem half
  f32x4 acc[4][4];
  #pragma unroll
  for (int a = 0; a < 4; ++a)
    #pragma unroll
    for (int b = 0; b < 4; ++b) acc[a][b] = (f32x4){0.f, 0.f, 0.f, 0.f};

  const float* xsrc = x + (size_t)(m0 + sr) * 784;
  const unsigned short* bhsrc = wt_hi + (size_t)(n0 + sr) * 800;
  const unsigned short* blsrc = wt_lo + (size_t)(n0 + sr) * 800;

  for (int kt = 0; kt < 25; ++kt) {
    const int kb = (kt << 5) + sh;
    // A stage: 16 fp32 -> bf16 (zero tail past K=784)
    float va[16];
    if (kb + 16 <= 784) {
      const float4* s = (const float4*)(xsrc + kb);
      #pragma unroll
      for (int q = 0; q < 4; ++q) {
        float4 f = s[q];
        va[q * 4 + 0] = f.x; va[q * 4 + 1] = f.y;
        va[q * 4 + 2] = f.z; va[q * 4 + 3] = f.w;
      }
    } else {
      #pragma unroll
      for (int q = 0; q < 16; ++q) va[q] = 0.f;
    }
    uint32_t pk[8];
    #pragma unroll
    for (int q = 0; q < 8; ++q)
      pk[q] = (uint32_t)f2bf(va[2 * q]) | ((uint32_t)f2bf(va[2 * q + 1]) << 16);
    uint4* adst = (uint4*)&As[sr][sh];
    adst[0] = make_uint4(pk[0], pk[1], pk[2], pk[3]);
    adst[1] = make_uint4(pk[4], pk[5], pk[6], pk[7]);
    // B stage: straight 32B copies (pre-packed bf16, already transposed+padded)
    const uint4* bh4 = (const uint4*)(bhsrc + kb);
    const uint4* bl4 = (const uint4*)(blsrc + kb);
    uint4* bhd = (uint4*)&Bh[sr][sh];
    uint4* bld = (uint4*)&Bl[sr][sh];
    bhd[0] = bh4[0]; bhd[1] = bh4[1];
    bld[0] = bl4[0]; bld[1] = bl4[1];
    __syncthreads();

    short8 af[4], bh[4], bl[4];
    #pragma unroll
    for (int mt = 0; mt < 4; ++mt)
      af[mt] = *(const short8*)&As[(wr << 6) + (mt << 4) + fm][fkb];
    #pragma unroll
    for (int nt = 0; nt < 4; ++nt) {
      bh[nt] = *(const short8*)&Bh[(wc << 6) + (nt << 4) + fm][fkb];
      bl[nt] = *(const short8*)&Bl[(wc << 6) + (nt << 4) + fm][fkb];
    }
    #pragma unroll
    for (int mt = 0; mt < 4; ++mt)
      #pragma unroll
      for (int nt = 0; nt < 4; ++nt) {
        acc[mt][nt] = __builtin_amdgcn_mfma_f32_16x16x32_bf16(af[mt], bh[nt], acc[mt][nt], 0, 0, 0);
        acc[mt][nt] = __builtin_amdgcn_mfma_f32_16x16x32_bf16(af[mt], bl[nt], acc[mt][nt], 0, 0, 0);
      }
    __syncthreads();
  }
  // epilogue: D row=(lane>>4)*4+r, col=lane&15 (m89-verified layout)
  const int rbase = (lane >> 4) << 2;
  #pragma unroll
  for (int mt = 0; mt < 4; ++mt)
    #pragma unroll
    for (int nt = 0; nt < 4; ++nt) {
      int col = n0 + (wc << 6) + (nt << 4) + fm;
      #pragma unroll
      for (int r = 0; r < 4; ++r) {
        int row = m0 + (wr << 6) + (mt << 4) + rbase + r;
        xw[(size_t)row * 1024 + col] = f2bf(acc[mt][nt][r]);
      }
    }
}

// ---- recurrent scan: 1 WG per batch, h/c resident, fused BN+tanh+FC ----
__global__ __launch_bounds__(256) void scan_kernel(
    const uint32_t* __restrict__ wrp, const unsigned short* __restrict__ xw,
    const float* __restrict__ bias, const float* __restrict__ wci,
    const float* __restrict__ wcf, const float* __restrict__ wco,
    const float* __restrict__ gamma, const float* __restrict__ beta,
    const float* __restrict__ mean, const float* __restrict__ var,
    const float* __restrict__ fcw, float* __restrict__ out) {
  __shared__ __align__(16) float h_lds[256];
  __shared__ __align__(16) float red[4][16];
  const int i = threadIdx.x;          // hidden index owned by this thread
  const int b = blockIdx.x;
  const int lane = i & 63, wv = i >> 6;
  const float b0 = bias[i], b1 = bias[256 + i], b2 = bias[512 + i], b3 = bias[768 + i];
  const float pci = wci[i], pcf = wcf[i], pco = wco[i];
  const float bna = gamma[i] * rsqrtf(var[i] + 1e-3f);
  const float bnb = beta[i] - mean[i] * bna;
  float fw[10];
  #pragma unroll
  for (int c = 0; c < 10; ++c) fw[c] = fcw[i * 10 + c];
  float cst = 0.f;
  h_lds[i] = 0.f;
  __syncthreads();
  const unsigned short* xwp = xw + ((size_t)b << 19);  // b*512*1024
  for (int t = 0; t < 512; ++t) {
    float a0 = 0.f, a1 = 0.f, a2 = 0.f, a3 = 0.f;
    const uint32_t* wp = wrp + i;
    const float2* hp = (const float2*)h_lds;
    #pragma unroll 4
    for (int kp = 0; kp < 128; ++kp) {
      float2 h2 = hp[kp];                 // LDS broadcast (uniform addr)
      uint32_t u0 = wp[0];                // coalesced dword loads, 4 gates
      uint32_t u1 = wp[256];
      uint32_t u2 = wp[512];
      uint32_t u3 = wp[768];
      a0 += h2.x * bflo(u0); a0 += h2.y * bfhi(u0);
      a1 += h2.x * bflo(u1); a1 += h2.y * bfhi(u1);
      a2 += h2.x * bflo(u2); a2 += h2.y * bfhi(u2);
      a3 += h2.x * bflo(u3); a3 += h2.y * bfhi(u3);
      wp += 1024;
    }
    const unsigned short* xr = xwp + (t << 10);
    float z0 = a0 + b0 + bfu2f(xr[i]);
    float z1 = a1 + b1 + bfu2f(xr[256 + i]);
    float z2 = a2 + b2 + bfu2f(xr[512 + i]);
    float z3 = a3 + b3 + bfu2f(xr[768 + i]);
    float ig = sigm(z0 + cst * pci);
    float fg = sigm(z1 + cst * pcf);
    float cn = fg * cst + ig * tanh_(z2);
    float og = sigm(z3 + cn * pco);
    float hn = og * tanh_(cn);
    cst = cn;
    __syncthreads();                      // all GEMV reads of h_t done
    h_lds[i] = hn;
    // fused BN -> tanh -> FC(10)
    float y = tanh_(hn * bna + bnb);
    float p[10];
    #pragma unroll
    for (int c = 0; c < 10; ++c) p[c] = y * fw[c];
    #pragma unroll
    for (int off = 32; off > 0; off >>= 1)
      #pragma unroll
      for (int c = 0; c < 10; ++c) p[c] += __shfl_down(p[c], off, 64);
    if (lane == 0)
      #pragma unroll
      for (int c = 0; c < 10; ++c) red[wv][c] = p[c];
    __syncthreads();                      // h_{t+1} visible + red visible
    if (i < 10)
      out[(((size_t)b << 9) + t) * 10 + i] =
          red[0][i] + red[1][i] + red[2][i] + red[3][i];
  }
}

extern "C" void kernel_launch(void* const* d_in, const int* in_sizes, int n_in,
                              void* d_out, int out_size, void* d_ws, size_t ws_size,
                              hipStream_t stream) {
  const float* x     = (const float*)d_in[0];
  const float* kw    = (const float*)d_in[1];
  const float* rk    = (const float*)d_in[2];
  const float* bias  = (const float*)d_in[3];
  const float* wci   = (const float*)d_in[4];
  const float* wcf   = (const float*)d_in[5];
  const float* wco   = (const float*)d_in[6];
  const float* gamma = (const float*)d_in[7];
  const float* beta  = (const float*)d_in[8];
  const float* mean  = (const float*)d_in[9];
  const float* var   = (const float*)d_in[10];
  const float* fcw   = (const float*)d_in[11];
  float* out = (float*)d_out;

  char* ws = (char*)d_ws;
  unsigned short* xw    = (unsigned short*)ws;                         // 134217728 B
  unsigned short* wt_hi = (unsigned short*)(ws + 134217728);           // 1638400 B
  unsigned short* wt_lo = (unsigned short*)(ws + 134217728 + 1638400); // 1638400 B
  uint32_t*       wrp   = (uint32_t*)(ws + 134217728 + 3276800);       // 524288 B
  // total ws need: ~138.0 MB

  repack_w<<<dim3((1024 * 800 + 255) / 256), dim3(256), 0, stream>>>(kw, wt_hi, wt_lo);
  repack_wr<<<dim3((128 * 1024 + 255) / 256), dim3(256), 0, stream>>>(rk, wrp);
  gemm_xw<<<dim3(8, 512), dim3(256), 0, stream>>>(x, wt_hi, wt_lo, xw);
  scan_kernel<<<dim3(128), dim3(256), 0, stream>>>(wrp, xw, bias, wci, wcf, wco,
                                                   gamma, beta, mean, var, fcw, out);
}

// Round 2
// 4563.506 us; speedup vs baseline: 1.0523x; 1.0523x over previous
//
#include <hip/hip_runtime.h>
#include <hip/hip_bf16.h>
#include <hip/hip_fp16.h>
#include <stdint.h>

// LSTMModelLite: B=128,T=512,F=784,H=256,C=10
// R2: scan rebuilt for occupancy + L2 BW:
//   - 1024 thr/WG (16 waves/CU), 1 output column n per thread
//   - weights repacked to f16 k-quads (uint2), v_dot2_f32_f16 inner loop
//   - first 16 k-quads (128 KB) cached in LDS, rest streamed from L2
//   - z exchanged via LDS; h kept as packed f16 in LDS; fused BN+tanh+FC
// ws layout: xw(f16) 134217728 B | wt_hi 1638400 | wt_lo 1638400 | wrp2 524288

typedef __attribute__((ext_vector_type(8))) short short8;
typedef __attribute__((ext_vector_type(4))) float f32x4;
typedef _Float16 half2_t __attribute__((ext_vector_type(2)));

__device__ __forceinline__ unsigned short f2bf(float f) {
  union { float f; uint32_t u; } v; v.f = f;
  return (unsigned short)((v.u + 0x7fffu + ((v.u >> 16) & 1u)) >> 16);
}
__device__ __forceinline__ float bfu2f(uint32_t u16) {
  union { uint32_t u; float f; } v; v.u = u16 << 16; return v.f;
}
__device__ __forceinline__ float sigm(float x) { return 1.f / (1.f + __expf(-x)); }
__device__ __forceinline__ float tanh_(float x) {
  float e = __expf(2.f * x);
  return 1.f - 2.f / (e + 1.f);
}
__device__ __forceinline__ float dot2f(uint32_t w, uint32_t h, float acc) {
#if __has_builtin(__builtin_amdgcn_fdot2)
  union { uint32_t u; half2_t v; } W, H;
  W.u = w; H.u = h;
  return __builtin_amdgcn_fdot2(W.v, H.v, acc, false);
#else
  union { uint32_t u; half2_t v; } W, H;
  W.u = w; H.u = h;
  return acc + (float)W.v.x * (float)H.v.x + (float)W.v.y * (float)H.v.y;
#endif
}

__global__ void repack_w(const float* __restrict__ w, unsigned short* __restrict__ wt_hi,
                         unsigned short* __restrict__ wt_lo) {
  int idx = blockIdx.x * 256 + threadIdx.x;  // n*800 + k
  if (idx >= 1024 * 800) return;
  int n = idx / 800, k = idx - n * 800;
  float v = (k < 784) ? w[k * 1024 + n] : 0.f;
  unsigned short hi = f2bf(v);
  wt_hi[idx] = hi;
  wt_lo[idx] = f2bf(v - bfu2f(hi));
}

// rec_kernel fp32 [256][1024] -> f16 k-quad pairs: wrp2[(kpp*1024+n)*2+{0,1}]
__global__ void repack_wr(const float* __restrict__ rk, uint32_t* __restrict__ wrp2) {
  int idx = blockIdx.x * 256 + threadIdx.x;  // kpp*1024 + n
  if (idx >= 64 * 1024) return;
  int kpp = idx >> 10, n = idx & 1023;
  const float* c = rk + n;
  uint32_t a0 = __half_as_ushort(__float2half(c[(4 * kpp + 0) << 10]));
  uint32_t a1 = __half_as_ushort(__float2half(c[(4 * kpp + 1) << 10]));
  uint32_t a2 = __half_as_ushort(__float2half(c[(4 * kpp + 2) << 10]));
  uint32_t a3 = __half_as_ushort(__float2half(c[(4 * kpp + 3) << 10]));
  wrp2[idx * 2 + 0] = a0 | (a1 << 16);
  wrp2[idx * 2 + 1] = a2 | (a3 << 16);
}

// ---- xw = x @ kernel ; BM=BN=128, BK=32, 256 thr, B split hi+lo (2 MFMAs) ----
__global__ __launch_bounds__(256, 2) void gemm_xw(
    const float* __restrict__ x, const unsigned short* __restrict__ wt_hi,
    const unsigned short* __restrict__ wt_lo, __half* __restrict__ xw) {
  __shared__ __align__(16) unsigned short As[128][40];
  __shared__ __align__(16) unsigned short Bh[128][40];
  __shared__ __align__(16) unsigned short Bl[128][40];
  const int tid = threadIdx.x;
  const int m0 = blockIdx.y << 7;
  const int n0 = blockIdx.x << 7;
  const int lane = tid & 63, wv = tid >> 6;
  const int wr = wv >> 1, wc = wv & 1;
  const int fm = lane & 15;
  const int fkb = (lane >> 4) << 3;
  const int sr = tid >> 1, sh = (tid & 1) << 4;
  f32x4 acc[4][4];
  #pragma unroll
  for (int a = 0; a < 4; ++a)
    #pragma unroll
    for (int b = 0; b < 4; ++b) acc[a][b] = (f32x4){0.f, 0.f, 0.f, 0.f};

  const float* xsrc = x + (size_t)(m0 + sr) * 784;
  const unsigned short* bhsrc = wt_hi + (size_t)(n0 + sr) * 800;
  const unsigned short* blsrc = wt_lo + (size_t)(n0 + sr) * 800;

  for (int kt = 0; kt < 25; ++kt) {
    const int kb = (kt << 5) + sh;
    float va[16];
    if (kb + 16 <= 784) {
      const float4* s = (const float4*)(xsrc + kb);
      #pragma unroll
      for (int q = 0; q < 4; ++q) {
        float4 f = s[q];
        va[q * 4 + 0] = f.x; va[q * 4 + 1] = f.y;
        va[q * 4 + 2] = f.z; va[q * 4 + 3] = f.w;
      }
    } else {
      #pragma unroll
      for (int q = 0; q < 16; ++q) va[q] = 0.f;
    }
    uint32_t pk[8];
    #pragma unroll
    for (int q = 0; q < 8; ++q)
      pk[q] = (uint32_t)f2bf(va[2 * q]) | ((uint32_t)f2bf(va[2 * q + 1]) << 16);
    uint4* adst = (uint4*)&As[sr][sh];
    adst[0] = make_uint4(pk[0], pk[1], pk[2], pk[3]);
    adst[1] = make_uint4(pk[4], pk[5], pk[6], pk[7]);
    const uint4* bh4 = (const uint4*)(bhsrc + kb);
    const uint4* bl4 = (const uint4*)(blsrc + kb);
    uint4* bhd = (uint4*)&Bh[sr][sh];
    uint4* bld = (uint4*)&Bl[sr][sh];
    bhd[0] = bh4[0]; bhd[1] = bh4[1];
    bld[0] = bl4[0]; bld[1] = bl4[1];
    __syncthreads();

    short8 af[4], bh[4], bl[4];
    #pragma unroll
    for (int mt = 0; mt < 4; ++mt)
      af[mt] = *(const short8*)&As[(wr << 6) + (mt << 4) + fm][fkb];
    #pragma unroll
    for (int nt = 0; nt < 4; ++nt) {
      bh[nt] = *(const short8*)&Bh[(wc << 6) + (nt << 4) + fm][fkb];
      bl[nt] = *(const short8*)&Bl[(wc << 6) + (nt << 4) + fm][fkb];
    }
    #pragma unroll
    for (int mt = 0; mt < 4; ++mt)
      #pragma unroll
      for (int nt = 0; nt < 4; ++nt) {
        acc[mt][nt] = __builtin_amdgcn_mfma_f32_16x16x32_bf16(af[mt], bh[nt], acc[mt][nt], 0, 0, 0);
        acc[mt][nt] = __builtin_amdgcn_mfma_f32_16x16x32_bf16(af[mt], bl[nt], acc[mt][nt], 0, 0, 0);
      }
    __syncthreads();
  }
  const int rbase = (lane >> 4) << 2;
  #pragma unroll
  for (int mt = 0; mt < 4; ++mt)
    #pragma unroll
    for (int nt = 0; nt < 4; ++nt) {
      int col = n0 + (wc << 6) + (nt << 4) + fm;
      #pragma unroll
      for (int r = 0; r < 4; ++r) {
        int row = m0 + (wr << 6) + (mt << 4) + rbase + r;
        xw[(size_t)row * 1024 + col] = __float2half(acc[mt][nt][r]);
      }
    }
}

// ---- recurrent scan: 1 WG/batch, 1024 thr, LDS weight cache, fused epilogue ----
__global__ __launch_bounds__(1024, 4) void scan_kernel(
    const uint32_t* __restrict__ wrp2, const __half* __restrict__ xw,
    const float* __restrict__ bias, const float* __restrict__ wci,
    const float* __restrict__ wcf, const float* __restrict__ wco,
    const float* __restrict__ gamma, const float* __restrict__ beta,
    const float* __restrict__ mean, const float* __restrict__ var,
    const float* __restrict__ fcw, float* __restrict__ out) {
  // LDS: weight cache (16 k-quads = k<64) 128 KB + z exchange + packed h + red
  __shared__ __align__(16) uint2 lw[16 * 1024];      // 131072 B
  __shared__ __align__(16) float zs[1024];           // 4096 B
  __shared__ __align__(16) _Float16 h_h[256];        // 512 B
  __shared__ __align__(16) float red[4][10];         // 160 B
  const int t = threadIdx.x;       // output column n = t (gate = t>>8, hidden = t&255)
  const int b = blockIdx.x;
  const int lane = t & 63, wv = t >> 6;

  const uint2* wsrc = (const uint2*)wrp2;
  #pragma unroll
  for (int kpp = 0; kpp < 16; ++kpp)
    lw[(kpp << 10) + t] = wsrc[(kpp << 10) + t];

  const float bn_ = bias[t];
  float pci = 0.f, pcf = 0.f, pco = 0.f, bna = 0.f, bnb = 0.f, cst = 0.f;
  float fw[10];
  if (t < 256) {
    pci = wci[t]; pcf = wcf[t]; pco = wco[t];
    bna = gamma[t] * rsqrtf(var[t] + 1e-3f);
    bnb = beta[t] - mean[t] * bna;
    #pragma unroll
    for (int c = 0; c < 10; ++c) fw[c] = fcw[t * 10 + c];
    h_h[t] = (_Float16)0.f;
  }
  __syncthreads();

  const __half* xwp = xw + ((size_t)b << 19);  // b*512*1024
  for (int tt = 0; tt < 512; ++tt) {
    // GEMV: z[n] = sum_k h[k] * Wr[k][n]
    float a = 0.f;
    const uint4* hq4 = (const uint4*)h_h;  // 32 entries: 2 k-quads each
    #pragma unroll 4
    for (int kq = 0; kq < 8; ++kq) {       // cached k-quads 0..15
      uint4 hv = hq4[kq];
      uint2 w0 = lw[((2 * kq) << 10) + t];
      uint2 w1 = lw[((2 * kq + 1) << 10) + t];
      a = dot2f(w0.x, hv.x, a); a = dot2f(w0.y, hv.y, a);
      a = dot2f(w1.x, hv.z, a); a = dot2f(w1.y, hv.w, a);
    }
    const uint2* wp = wsrc + (16 << 10) + t;  // streamed k-quads 16..63
    #pragma unroll 4
    for (int kq = 8; kq < 32; ++kq) {
      uint4 hv = hq4[kq];
      uint2 w0 = wp[0];
      uint2 w1 = wp[1024];
      wp += 2048;
      a = dot2f(w0.x, hv.x, a); a = dot2f(w0.y, hv.y, a);
      a = dot2f(w1.x, hv.z, a); a = dot2f(w1.y, hv.w, a);
    }
    zs[t] = a + bn_ + __half2float(xwp[((size_t)tt << 10) + t]);
    __syncthreads();

    if (t < 256) {
      float z0 = zs[t], z1 = zs[256 + t], z2 = zs[512 + t], z3 = zs[768 + t];
      float ig = sigm(z0 + cst * pci);
      float fg = sigm(z1 + cst * pcf);
      float cn = fg * cst + ig * tanh_(z2);
      float og = sigm(z3 + cn * pco);
      float hn = og * tanh_(cn);
      cst = cn;
      h_h[t] = (_Float16)hn;
      // fused BN -> tanh -> FC(10)
      float y = tanh_(hn * bna + bnb);
      float p[10];
      #pragma unroll
      for (int c = 0; c < 10; ++c) p[c] = y * fw[c];
      #pragma unroll
      for (int off = 32; off > 0; off >>= 1)
        #pragma unroll
        for (int c = 0; c < 10; ++c) p[c] += __shfl_down(p[c], off, 64);
      if (lane == 0)
        #pragma unroll
        for (int c = 0; c < 10; ++c) red[wv][c] = p[c];
    }
    __syncthreads();
    if (t < 10)
      out[(((size_t)b << 9) + tt) * 10 + t] =
          red[0][t] + red[1][t] + red[2][t] + red[3][t];
  }
}

extern "C" void kernel_launch(void* const* d_in, const int* in_sizes, int n_in,
                              void* d_out, int out_size, void* d_ws, size_t ws_size,
                              hipStream_t stream) {
  const float* x     = (const float*)d_in[0];
  const float* kw    = (const float*)d_in[1];
  const float* rk    = (const float*)d_in[2];
  const float* bias  = (const float*)d_in[3];
  const float* wci   = (const float*)d_in[4];
  const float* wcf   = (const float*)d_in[5];
  const float* wco   = (const float*)d_in[6];
  const float* gamma = (const float*)d_in[7];
  const float* beta  = (const float*)d_in[8];
  const float* mean  = (const float*)d_in[9];
  const float* var   = (const float*)d_in[10];
  const float* fcw   = (const float*)d_in[11];
  float* out = (float*)d_out;

  char* ws = (char*)d_ws;
  __half*         xw    = (__half*)ws;                                 // 134217728 B
  unsigned short* wt_hi = (unsigned short*)(ws + 134217728);           // 1638400 B
  unsigned short* wt_lo = (unsigned short*)(ws + 134217728 + 1638400); // 1638400 B
  uint32_t*       wrp2  = (uint32_t*)(ws + 134217728 + 3276800);       // 524288 B

  repack_w<<<dim3((1024 * 800 + 255) / 256), dim3(256), 0, stream>>>(kw, wt_hi, wt_lo);
  repack_wr<<<dim3((64 * 1024 + 255) / 256), dim3(256), 0, stream>>>(rk, wrp2);
  gemm_xw<<<dim3(8, 512), dim3(256), 0, stream>>>(x, wt_hi, wt_lo, xw);
  scan_kernel<<<dim3(128), dim3(1024), 0, stream>>>(wrp2, xw, bias, wci, wcf, wco,
                                                    gamma, beta, mean, var, fcw, out);
}

// Round 3
// 3416.514 us; speedup vs baseline: 1.4056x; 1.3357x over previous
//
#include <hip/hip_runtime.h>
#include <hip/hip_bf16.h>
#include <hip/hip_fp16.h>
#include <stdint.h>

// LSTMModelLite: B=128,T=512,F=784,H=256,C=10
// R3: weight-resident persistent scan.
//   - 32 WGs = 8 batch-groups x 4 WGs; group on one XCD (gr = blockIdx&7)
//   - WG g owns 256 cols (j in [64g,64g+64) x 4 gates); Wr slice lives in VGPRs
//     as MFMA B-frags (64 VGPRs/thread), loaded once; 16 MFMAs/wave/step
//   - h exchange: 2KB slice, double-buffered pub in global, agent-scope
//     atomics + flag release/acquire; LDS h_all for A-frags
//   - FC deferred: y=tanh(BN(h)) overwrites consumed xw cols 0..255; final
//     wave-per-row kernel computes logits
// ws: xw 134217728 | wt_hi 1638400 (pub/flags overlay after gemm) | wt_lo
//     1638400 | wfrag 524288  => 138,018,816 B total (== R1/R2 footprint)

typedef __attribute__((ext_vector_type(8))) short short8;
typedef __attribute__((ext_vector_type(4))) float f32x4;

__device__ __forceinline__ unsigned short f2bf(float f) {
  union { float f; uint32_t u; } v; v.f = f;
  return (unsigned short)((v.u + 0x7fffu + ((v.u >> 16) & 1u)) >> 16);
}
__device__ __forceinline__ float bfu2f(uint32_t u16) {
  union { uint32_t u; float f; } v; v.u = u16 << 16; return v.f;
}
__device__ __forceinline__ float sigm(float x) { return 1.f / (1.f + __expf(-x)); }
__device__ __forceinline__ float tanh_(float x) {
  float e = __expf(2.f * x);
  return 1.f - 2.f / (e + 1.f);
}

__global__ void repack_w(const float* __restrict__ w, unsigned short* __restrict__ wt_hi,
                         unsigned short* __restrict__ wt_lo) {
  int idx = blockIdx.x * 256 + threadIdx.x;  // n*800 + k
  if (idx >= 1024 * 800) return;
  int n = idx / 800, k = idx - n * 800;
  float v = (k < 784) ? w[k * 1024 + n] : 0.f;
  unsigned short hi = f2bf(v);
  wt_hi[idx] = hi;
  wt_lo[idx] = f2bf(v - bfu2f(hi));
}

// rec_kernel fp32 [256 j][1024 n] -> MFMA B-frags per (wg g, tile nt, kstep, lane)
__global__ void repack_wf(const float* __restrict__ rk, unsigned short* __restrict__ wf) {
  int idx = blockIdx.x * 256 + threadIdx.x;  // (g,nt,ks,lane): 4*16*8*64 = 32768
  if (idx >= 32768) return;
  int lane = idx & 63, ks = (idx >> 6) & 7, nt = (idx >> 9) & 15, g = (idx >> 13) & 3;
  int np = nt * 16 + (lane & 15);                    // local col 0..255
  int ncol = (np >> 6) * 256 + g * 64 + (np & 63);   // global col (gate,j)
  int kb = ks * 32 + ((lane >> 4) << 3);             // global k (= hidden j_prev)
  union { unsigned short s[8]; uint4 v; } u;
  #pragma unroll
  for (int q = 0; q < 8; ++q) u.s[q] = f2bf(rk[(size_t)(kb + q) * 1024 + ncol]);
  ((uint4*)wf)[idx] = u.v;
}

// ---- xw = x @ kernel ; BM=BN=128, BK=32, 256 thr, B split hi+lo (2 MFMAs) ----
__global__ __launch_bounds__(256, 2) void gemm_xw(
    const float* __restrict__ x, const unsigned short* __restrict__ wt_hi,
    const unsigned short* __restrict__ wt_lo, __half* __restrict__ xw) {
  __shared__ __align__(16) unsigned short As[128][40];
  __shared__ __align__(16) unsigned short Bh[128][40];
  __shared__ __align__(16) unsigned short Bl[128][40];
  const int tid = threadIdx.x;
  const int m0 = blockIdx.y << 7;
  const int n0 = blockIdx.x << 7;
  const int lane = tid & 63, wv = tid >> 6;
  const int wr = wv >> 1, wc = wv & 1;
  const int fm = lane & 15;
  const int fkb = (lane >> 4) << 3;
  const int sr = tid >> 1, sh = (tid & 1) << 4;
  f32x4 acc[4][4];
  #pragma unroll
  for (int a = 0; a < 4; ++a)
    #pragma unroll
    for (int b = 0; b < 4; ++b) acc[a][b] = (f32x4){0.f, 0.f, 0.f, 0.f};

  const float* xsrc = x + (size_t)(m0 + sr) * 784;
  const unsigned short* bhsrc = wt_hi + (size_t)(n0 + sr) * 800;
  const unsigned short* blsrc = wt_lo + (size_t)(n0 + sr) * 800;

  for (int kt = 0; kt < 25; ++kt) {
    const int kb = (kt << 5) + sh;
    float va[16];
    if (kb + 16 <= 784) {
      const float4* s = (const float4*)(xsrc + kb);
      #pragma unroll
      for (int q = 0; q < 4; ++q) {
        float4 f = s[q];
        va[q * 4 + 0] = f.x; va[q * 4 + 1] = f.y;
        va[q * 4 + 2] = f.z; va[q * 4 + 3] = f.w;
      }
    } else {
      #pragma unroll
      for (int q = 0; q < 16; ++q) va[q] = 0.f;
    }
    uint32_t pk[8];
    #pragma unroll
    for (int q = 0; q < 8; ++q)
      pk[q] = (uint32_t)f2bf(va[2 * q]) | ((uint32_t)f2bf(va[2 * q + 1]) << 16);
    uint4* adst = (uint4*)&As[sr][sh];
    adst[0] = make_uint4(pk[0], pk[1], pk[2], pk[3]);
    adst[1] = make_uint4(pk[4], pk[5], pk[6], pk[7]);
    const uint4* bh4 = (const uint4*)(bhsrc + kb);
    const uint4* bl4 = (const uint4*)(blsrc + kb);
    uint4* bhd = (uint4*)&Bh[sr][sh];
    uint4* bld = (uint4*)&Bl[sr][sh];
    bhd[0] = bh4[0]; bhd[1] = bh4[1];
    bld[0] = bl4[0]; bld[1] = bl4[1];
    __syncthreads();

    short8 af[4], bh[4], bl[4];
    #pragma unroll
    for (int mt = 0; mt < 4; ++mt)
      af[mt] = *(const short8*)&As[(wr << 6) + (mt << 4) + fm][fkb];
    #pragma unroll
    for (int nt = 0; nt < 4; ++nt) {
      bh[nt] = *(const short8*)&Bh[(wc << 6) + (nt << 4) + fm][fkb];
      bl[nt] = *(const short8*)&Bl[(wc << 6) + (nt << 4) + fm][fkb];
    }
    #pragma unroll
    for (int mt = 0; mt < 4; ++mt)
      #pragma unroll
      for (int nt = 0; nt < 4; ++nt) {
        acc[mt][nt] = __builtin_amdgcn_mfma_f32_16x16x32_bf16(af[mt], bh[nt], acc[mt][nt], 0, 0, 0);
        acc[mt][nt] = __builtin_amdgcn_mfma_f32_16x16x32_bf16(af[mt], bl[nt], acc[mt][nt], 0, 0, 0);
      }
    __syncthreads();
  }
  const int rbase = (lane >> 4) << 2;
  #pragma unroll
  for (int mt = 0; mt < 4; ++mt)
    #pragma unroll
    for (int nt = 0; nt < 4; ++nt) {
      int col = n0 + (wc << 6) + (nt << 4) + fm;
      #pragma unroll
      for (int r = 0; r < 4; ++r) {
        int row = m0 + (wr << 6) + (mt << 4) + rbase + r;
        xw[(size_t)row * 1024 + col] = __float2half(acc[mt][nt][r]);
      }
    }
}

__global__ void init_flags(int* flags) {
  if (threadIdx.x < 32) flags[threadIdx.x] = 0;
}

// ---- persistent recurrent scan ----
__global__ __launch_bounds__(512, 2) void scan_kernel(
    const unsigned short* __restrict__ wf, __half* __restrict__ xw,
    uint32_t* __restrict__ pub, int* __restrict__ flags,
    const float* __restrict__ bias, const float* __restrict__ wci,
    const float* __restrict__ wcf, const float* __restrict__ wco,
    const float* __restrict__ gamma, const float* __restrict__ beta,
    const float* __restrict__ mean, const float* __restrict__ var) {
  __shared__ __align__(16) unsigned short h_all[16][264];  // global j, pad row to 528B
  __shared__ __align__(16) float zbuf[16 * 260];           // [b][n' local], pad 260
  const int tid = threadIdx.x;
  const int lane = tid & 63, w = tid >> 6;
  const int gr = blockIdx.x & 7;   // batch-group (XCD-colocated: blockIdx%8 -> XCD)
  const int g = blockIdx.x >> 3;   // position in group: owns j in [64g,64g+64)

  // --- resident weight B-frags: tiles 2w, 2w+1 ---
  short8 bw0[8], bw1[8];
  {
    const unsigned short* wb = wf + (size_t)(g * 16 + 2 * w) * 4096;  // 8*64*8 per tile
    #pragma unroll
    for (int ks = 0; ks < 8; ++ks) {
      bw0[ks] = *(const short8*)(wb + (ks * 64 + lane) * 8);
      bw1[ks] = *(const short8*)(wb + 4096 + (ks * 64 + lane) * 8);
    }
  }

  // --- gate-phase per-thread constants: (jj, 2 batches) ---
  const int jj = tid & 63, bp = tid >> 6;
  const int jg = g * 64 + jj;  // global hidden index
  const float b0 = bias[jg], b1 = bias[256 + jg], b2 = bias[512 + jg], b3 = bias[768 + jg];
  const float pci = wci[jg], pcf = wcf[jg], pco = wco[jg];
  const float bna = gamma[jg] * rsqrtf(var[jg] + 1e-3f);
  const float bnb = beta[jg] - mean[jg] * bna;
  float c2[2] = {0.f, 0.f};
  uint32_t* mypub0 = pub + (size_t)(gr * 4 + g) * 512 + jj * 8 + bp;
  int* myflag = flags + gr * 4 + g;

  for (int t = 0; t < 512; ++t) {
    if (t > 0) {
      // wait for peers' h(t), stage into h_all
      if (tid == 0) {
        long gcnt = 0;
        #pragma unroll
        for (int p = 0; p < 4; ++p) {
          if (p == g) continue;
          while (__hip_atomic_load(flags + gr * 4 + p, __ATOMIC_ACQUIRE,
                                   __HIP_MEMORY_SCOPE_AGENT) < t) {
            if (++gcnt > (1L << 23)) break;  // bail-out: no infinite hang
          }
        }
      }
      __syncthreads();
      {
        const uint32_t* ps = pub + (size_t)(t & 1) * 16384 + (size_t)(gr * 4) * 512;
        int sj = tid >> 3, sb = tid & 7;
        #pragma unroll
        for (int p = 0; p < 4; ++p) {
          if (p == g) continue;
          uint32_t v = __hip_atomic_load(ps + p * 512 + tid, __ATOMIC_RELAXED,
                                         __HIP_MEMORY_SCOPE_AGENT);
          h_all[2 * sb][64 * p + sj] = (unsigned short)(v & 0xffffu);
          h_all[2 * sb + 1][64 * p + sj] = (unsigned short)(v >> 16);
        }
      }
      __syncthreads();
      // z = h(t) @ WrSlice  (A-frags from LDS, resident B-frags)
      short8 af[8];
      #pragma unroll
      for (int ks = 0; ks < 8; ++ks)
        af[ks] = *(const short8*)&h_all[lane & 15][ks * 32 + ((lane >> 4) << 3)];
      f32x4 a0 = (f32x4){0.f, 0.f, 0.f, 0.f}, a1 = a0;
      #pragma unroll
      for (int ks = 0; ks < 8; ++ks) {
        a0 = __builtin_amdgcn_mfma_f32_16x16x32_bf16(af[ks], bw0[ks], a0, 0, 0, 0);
        a1 = __builtin_amdgcn_mfma_f32_16x16x32_bf16(af[ks], bw1[ks], a1, 0, 0, 0);
      }
      const int cb = (w << 5) + (lane & 15);
      const int rb = (lane >> 4) << 2;
      #pragma unroll
      for (int r = 0; r < 4; ++r) {
        zbuf[(rb + r) * 260 + cb] = a0[r];
        zbuf[(rb + r) * 260 + cb + 16] = a1[r];
      }
      __syncthreads();
    }
    // gate phase: thread -> (jj, batches 2bp, 2bp+1)
    float hn2[2];
    #pragma unroll
    for (int q = 0; q < 2; ++q) {
      const int bl = bp * 2 + q;
      const size_t xrow = (((size_t)(gr * 16 + bl) << 9) + t) << 10;
      float z0 = b0 + __half2float(xw[xrow + jg]);
      float z1 = b1 + __half2float(xw[xrow + 256 + jg]);
      float z2 = b2 + __half2float(xw[xrow + 512 + jg]);
      float z3 = b3 + __half2float(xw[xrow + 768 + jg]);
      if (t > 0) {
        z0 += zbuf[bl * 260 + jj];
        z1 += zbuf[bl * 260 + 64 + jj];
        z2 += zbuf[bl * 260 + 128 + jj];
        z3 += zbuf[bl * 260 + 192 + jj];
      }
      float ig = sigm(z0 + c2[q] * pci);
      float fg = sigm(z1 + c2[q] * pcf);
      float cn = fg * c2[q] + ig * tanh_(z2);
      float og = sigm(z3 + cn * pco);
      float hn = og * tanh_(cn);
      c2[q] = cn;
      hn2[q] = hn;
      h_all[bl][jg] = f2bf(hn);
      float y = tanh_(hn * bna + bnb);
      xw[xrow + jg] = __float2half(y);  // col jg<256: consumed above, y for final FC
    }
    if (t < 511) {
      uint32_t pv = (uint32_t)f2bf(hn2[0]) | ((uint32_t)f2bf(hn2[1]) << 16);
      __hip_atomic_store(mypub0 + (size_t)((t + 1) & 1) * 16384, pv,
                         __ATOMIC_RELAXED, __HIP_MEMORY_SCOPE_AGENT);
    }
    __syncthreads();  // h_all self writes visible; pub stores drained (barrier waits vmcnt)
    if (tid == 0 && t < 511)
      __hip_atomic_store(myflag, t + 1, __ATOMIC_RELEASE, __HIP_MEMORY_SCOPE_AGENT);
  }
}

// ---- final FC: out[b,t,c] = sum_j y[b,t,j] * fcw[j,c]; wave per row ----
__global__ __launch_bounds__(256) void final_fc(const __half* __restrict__ xw,
                                                const float* __restrict__ fcw,
                                                float* __restrict__ out) {
  const int tid = threadIdx.x, lane = tid & 63, w = tid >> 6;
  const int wid = blockIdx.x * 4 + w;  // 512 waves
  float fw[4][10];
  #pragma unroll
  for (int q = 0; q < 4; ++q)
    #pragma unroll
    for (int c = 0; c < 10; ++c) fw[q][c] = fcw[(lane * 4 + q) * 10 + c];
  for (int it = 0; it < 128; ++it) {
    const int row = it * 512 + wid;
    uint2 u = *(const uint2*)(xw + ((size_t)row << 10) + lane * 4);
    const __half* hp = (const __half*)&u;
    float y0 = __half2float(hp[0]), y1 = __half2float(hp[1]);
    float y2 = __half2float(hp[2]), y3 = __half2float(hp[3]);
    float p[10];
    #pragma unroll
    for (int c = 0; c < 10; ++c)
      p[c] = y0 * fw[0][c] + y1 * fw[1][c] + y2 * fw[2][c] + y3 * fw[3][c];
    #pragma unroll
    for (int off = 1; off < 64; off <<= 1)
      #pragma unroll
      for (int c = 0; c < 10; ++c) p[c] += __shfl_xor(p[c], off, 64);
    if (lane == 0) {
      #pragma unroll
      for (int c = 0; c < 10; ++c) out[(size_t)row * 10 + c] = p[c];
    }
  }
}

extern "C" void kernel_launch(void* const* d_in, const int* in_sizes, int n_in,
                              void* d_out, int out_size, void* d_ws, size_t ws_size,
                              hipStream_t stream) {
  const float* x     = (const float*)d_in[0];
  const float* kw    = (const float*)d_in[1];
  const float* rk    = (const float*)d_in[2];
  const float* bias  = (const float*)d_in[3];
  const float* wci   = (const float*)d_in[4];
  const float* wcf   = (const float*)d_in[5];
  const float* wco   = (const float*)d_in[6];
  const float* gamma = (const float*)d_in[7];
  const float* beta  = (const float*)d_in[8];
  const float* mean  = (const float*)d_in[9];
  const float* var   = (const float*)d_in[10];
  const float* fcw   = (const float*)d_in[11];
  float* out = (float*)d_out;

  char* ws = (char*)d_ws;
  __half*         xw    = (__half*)ws;                                 // 134217728 B
  unsigned short* wt_hi = (unsigned short*)(ws + 134217728);           // 1638400 B
  unsigned short* wt_lo = (unsigned short*)(ws + 134217728 + 1638400); // 1638400 B
  unsigned short* wfrag = (unsigned short*)(ws + 134217728 + 3276800); // 524288 B
  // pub/flags overlay wt_hi (dead after gemm_xw): pub 2*32*512*4=131072 B, flags 128 B
  uint32_t* pub   = (uint32_t*)(ws + 134217728);
  int*      flags = (int*)(ws + 134217728 + 131072);

  repack_w<<<dim3((1024 * 800 + 255) / 256), dim3(256), 0, stream>>>(kw, wt_hi, wt_lo);
  repack_wf<<<dim3(128), dim3(256), 0, stream>>>(rk, wfrag);
  gemm_xw<<<dim3(8, 512), dim3(256), 0, stream>>>(x, wt_hi, wt_lo, xw);
  init_flags<<<dim3(1), dim3(64), 0, stream>>>(flags);
  scan_kernel<<<dim3(32), dim3(512), 0, stream>>>(wfrag, xw, pub, flags, bias,
                                                  wci, wcf, wco, gamma, beta, mean, var);
  final_fc<<<dim3(128), dim3(256), 0, stream>>>(xw, fcw, out);
}

// Round 4
// 2320.901 us; speedup vs baseline: 2.0692x; 1.4721x over previous
//
#include <hip/hip_runtime.h>
#include <hip/hip_bf16.h>
#include <hip/hip_fp16.h>
#include <stdint.h>

// LSTMModelLite: B=128,T=512,F=784,H=256,C=10
// R4: fence-free persistent scan.
//   - 32 WGs = 8 batch-groups x 4 WGs (gr = blockIdx&7 -> same XCD per group)
//   - WG g owns cols {G*256 + g*64 + jj}; Wr slice resident in regs (128/thread)
//   - wave w owns tiles {w,w+4,w+8,w+12} => all 4 gates of jj=16w+c in one lane
//     -> gates computed in MFMA C-layout regs, no zbuf, 2 barriers/step
//   - h exchange: RELAXED agent-scope u64 atomics, tag embedded (no
//     acquire/release => no buffer_wb/buffer_inv L2 storms), parity dbuf
//   - xw gate inputs prefetched 1 step ahead; publish overlapped with gates
// ws: xw 134217728 | pub 262144 (overlay wt_hi 1638400, dead after gemm) |
//     wt_lo 1638400 | wfrag 524288

typedef __attribute__((ext_vector_type(8))) short short8;
typedef __attribute__((ext_vector_type(4))) float f32x4;

__device__ __forceinline__ unsigned short f2bf(float f) {
  union { float f; uint32_t u; } v; v.f = f;
  return (unsigned short)((v.u + 0x7fffu + ((v.u >> 16) & 1u)) >> 16);
}
__device__ __forceinline__ float bfu2f(uint32_t u16) {
  union { uint32_t u; float f; } v; v.u = u16 << 16; return v.f;
}
__device__ __forceinline__ float sigm(float x) { return 1.f / (1.f + __expf(-x)); }
__device__ __forceinline__ float tanh_(float x) {
  float e = __expf(2.f * x);
  return 1.f - 2.f / (e + 1.f);
}

__global__ void repack_w(const float* __restrict__ w, unsigned short* __restrict__ wt_hi,
                         unsigned short* __restrict__ wt_lo) {
  int idx = blockIdx.x * 256 + threadIdx.x;  // n*800 + k
  if (idx >= 1024 * 800) return;
  int n = idx / 800, k = idx - n * 800;
  float v = (k < 784) ? w[k * 1024 + n] : 0.f;
  unsigned short hi = f2bf(v);
  wt_hi[idx] = hi;
  wt_lo[idx] = f2bf(v - bfu2f(hi));
}

// rec_kernel fp32 [256 k][1024 n] -> B-frags indexed (g,w,G,ks,lane,8)
__global__ void repack_wf(const float* __restrict__ rk, unsigned short* __restrict__ wf) {
  int idx = blockIdx.x * 256 + threadIdx.x;  // 4g*4w*4G*8ks*64lane = 32768
  if (idx >= 32768) return;
  int lane = idx & 63, ks = (idx >> 6) & 7, G = (idx >> 9) & 3;
  int w = (idx >> 11) & 3, g = (idx >> 13) & 3;
  int ncol = G * 256 + g * 64 + 16 * w + (lane & 15);
  int kb = ks * 32 + ((lane >> 4) << 3);
  union { unsigned short s[8]; uint4 v; } u;
  #pragma unroll
  for (int e = 0; e < 8; ++e) u.s[e] = f2bf(rk[(size_t)(kb + e) * 1024 + ncol]);
  ((uint4*)wf)[idx] = u.v;
}

// ---- xw = x @ kernel ; BM=BN=128, BK=32, 256 thr, B split hi+lo (2 MFMAs) ----
__global__ __launch_bounds__(256, 2) void gemm_xw(
    const float* __restrict__ x, const unsigned short* __restrict__ wt_hi,
    const unsigned short* __restrict__ wt_lo, __half* __restrict__ xw) {
  __shared__ __align__(16) unsigned short As[128][40];
  __shared__ __align__(16) unsigned short Bh[128][40];
  __shared__ __align__(16) unsigned short Bl[128][40];
  const int tid = threadIdx.x;
  const int m0 = blockIdx.y << 7;
  const int n0 = blockIdx.x << 7;
  const int lane = tid & 63, wv = tid >> 6;
  const int wr = wv >> 1, wc = wv & 1;
  const int fm = lane & 15;
  const int fkb = (lane >> 4) << 3;
  const int sr = tid >> 1, sh = (tid & 1) << 4;
  f32x4 acc[4][4];
  #pragma unroll
  for (int a = 0; a < 4; ++a)
    #pragma unroll
    for (int b = 0; b < 4; ++b) acc[a][b] = (f32x4){0.f, 0.f, 0.f, 0.f};

  const float* xsrc = x + (size_t)(m0 + sr) * 784;
  const unsigned short* bhsrc = wt_hi + (size_t)(n0 + sr) * 800;
  const unsigned short* blsrc = wt_lo + (size_t)(n0 + sr) * 800;

  for (int kt = 0; kt < 25; ++kt) {
    const int kb = (kt << 5) + sh;
    float va[16];
    if (kb + 16 <= 784) {
      const float4* s = (const float4*)(xsrc + kb);
      #pragma unroll
      for (int q = 0; q < 4; ++q) {
        float4 f = s[q];
        va[q * 4 + 0] = f.x; va[q * 4 + 1] = f.y;
        va[q * 4 + 2] = f.z; va[q * 4 + 3] = f.w;
      }
    } else {
      #pragma unroll
      for (int q = 0; q < 16; ++q) va[q] = 0.f;
    }
    uint32_t pk[8];
    #pragma unroll
    for (int q = 0; q < 8; ++q)
      pk[q] = (uint32_t)f2bf(va[2 * q]) | ((uint32_t)f2bf(va[2 * q + 1]) << 16);
    uint4* adst = (uint4*)&As[sr][sh];
    adst[0] = make_uint4(pk[0], pk[1], pk[2], pk[3]);
    adst[1] = make_uint4(pk[4], pk[5], pk[6], pk[7]);
    const uint4* bh4 = (const uint4*)(bhsrc + kb);
    const uint4* bl4 = (const uint4*)(blsrc + kb);
    uint4* bhd = (uint4*)&Bh[sr][sh];
    uint4* bld = (uint4*)&Bl[sr][sh];
    bhd[0] = bh4[0]; bhd[1] = bh4[1];
    bld[0] = bl4[0]; bld[1] = bl4[1];
    __syncthreads();

    short8 af[4], bh[4], bl[4];
    #pragma unroll
    for (int mt = 0; mt < 4; ++mt)
      af[mt] = *(const short8*)&As[(wr << 6) + (mt << 4) + fm][fkb];
    #pragma unroll
    for (int nt = 0; nt < 4; ++nt) {
      bh[nt] = *(const short8*)&Bh[(wc << 6) + (nt << 4) + fm][fkb];
      bl[nt] = *(const short8*)&Bl[(wc << 6) + (nt << 4) + fm][fkb];
    }
    #pragma unroll
    for (int mt = 0; mt < 4; ++mt)
      #pragma unroll
      for (int nt = 0; nt < 4; ++nt) {
        acc[mt][nt] = __builtin_amdgcn_mfma_f32_16x16x32_bf16(af[mt], bh[nt], acc[mt][nt], 0, 0, 0);
        acc[mt][nt] = __builtin_amdgcn_mfma_f32_16x16x32_bf16(af[mt], bl[nt], acc[mt][nt], 0, 0, 0);
      }
    __syncthreads();
  }
  const int rbase = (lane >> 4) << 2;
  #pragma unroll
  for (int mt = 0; mt < 4; ++mt)
    #pragma unroll
    for (int nt = 0; nt < 4; ++nt) {
      int col = n0 + (wc << 6) + (nt << 4) + fm;
      #pragma unroll
      for (int r = 0; r < 4; ++r) {
        int row = m0 + (wr << 6) + (mt << 4) + rbase + r;
        xw[(size_t)row * 1024 + col] = __float2half(acc[mt][nt][r]);
      }
    }
}

// ---- fence-free persistent recurrent scan ----
__global__ __launch_bounds__(256, 1) void scan_kernel(
    const unsigned short* __restrict__ wf, __half* __restrict__ xw,
    unsigned long long* __restrict__ pub,
    const float* __restrict__ bias, const float* __restrict__ wci,
    const float* __restrict__ wcf, const float* __restrict__ wco,
    const float* __restrict__ gamma, const float* __restrict__ beta,
    const float* __restrict__ mean, const float* __restrict__ var) {
  __shared__ __align__(16) unsigned short h_all[16][264];
  const int tid = threadIdx.x, lane = tid & 63, w = tid >> 6;
  const int gr = blockIdx.x & 7;   // batch-group (same XCD via %8 round-robin)
  const int g = blockIdx.x >> 3;   // member: owns jj in [0,64) -> jg = 64g+jj
  const int c = lane & 15, q = lane >> 4;
  const int jj = 16 * w + c, jg = 64 * g + jj;

  // resident weight B-frags: tiles {w, w+4, w+8, w+12} (gate G = tile>>2)
  short8 bw[4][8];
  {
    const unsigned short* wb = wf + (size_t)(g * 4 + w) * 16384;
    #pragma unroll
    for (int G = 0; G < 4; ++G)
      #pragma unroll
      for (int ks = 0; ks < 8; ++ks)
        bw[G][ks] = *(const short8*)(wb + (size_t)((G * 8 + ks) * 64 + lane) * 8);
  }

  const float b0 = bias[jg], b1 = bias[256 + jg], b2 = bias[512 + jg], b3 = bias[768 + jg];
  const float pci = wci[jg], pcf = wcf[jg], pco = wco[jg];
  const float bna = gamma[jg] * rsqrtf(var[jg] + 1e-3f);
  const float bnb = beta[jg] - mean[jg] * bna;
  float c2[4] = {0.f, 0.f, 0.f, 0.f};

  unsigned long long* mypub = pub + (size_t)(gr * 4 + g) * 512 + jj * 8 + q * 2;
  const size_t xbase = ((size_t)(gr * 16 + 4 * q) << 9);  // row of batch 4q, t=0

  // prefetch xw for s=0
  float xp[4][4];
  #pragma unroll
  for (int G = 0; G < 4; ++G)
    #pragma unroll
    for (int r = 0; r < 4; ++r)
      xp[G][r] = __half2float(xw[((xbase + ((size_t)r << 9)) << 10) + G * 256 + jg]);

  for (int s = 0; s < 512; ++s) {
    f32x4 acc[4];
    #pragma unroll
    for (int G = 0; G < 4; ++G) acc[G] = (f32x4){0.f, 0.f, 0.f, 0.f};

    if (s > 0) {
      // poll peers' tagged h(s) words (relaxed, agent scope — no fences)
      unsigned long long vv[6];
      unsigned need = 63u;
      long cnt = 0;
      const size_t slot = (size_t)(s & 1) * 16384;
      while (need) {
        #pragma unroll
        for (int pp = 0; pp < 3; ++pp) {
          int p = (g + 1 + pp) & 3;
          #pragma unroll
          for (int u2 = 0; u2 < 2; ++u2) {
            int bit = pp * 2 + u2;
            if (need & (1u << bit)) {
              unsigned long long v = __hip_atomic_load(
                  pub + slot + (size_t)(gr * 4 + p) * 512 + 2 * tid + u2,
                  __ATOMIC_RELAXED, __HIP_MEMORY_SCOPE_AGENT);
              if ((unsigned)(v >> 32) == (unsigned)s) {
                vv[bit] = v;
                need &= ~(1u << bit);
              }
            }
          }
        }
        if (++cnt > (1L << 22)) break;  // bounded: no infinite hang
      }
      // stage peer h into h_all
      #pragma unroll
      for (int pp = 0; pp < 3; ++pp) {
        int p = (g + 1 + pp) & 3;
        #pragma unroll
        for (int u2 = 0; u2 < 2; ++u2) {
          int wid = 2 * tid + u2;
          unsigned long long v = vv[pp * 2 + u2];
          int jj2 = wid >> 3, qq = (wid >> 1) & 3, uu = wid & 1;
          int m0 = 4 * qq + 2 * uu, col = 64 * p + jj2;
          h_all[m0][col] = (unsigned short)(v & 0xffffu);
          h_all[m0 + 1][col] = (unsigned short)((v >> 16) & 0xffffu);
        }
      }
      __syncthreads();
      // z_rec = h(s) @ WrSlice
      short8 af[8];
      #pragma unroll
      for (int ks = 0; ks < 8; ++ks)
        af[ks] = *(const short8*)&h_all[c][ks * 32 + q * 8];
      #pragma unroll
      for (int ks = 0; ks < 8; ++ks)
        #pragma unroll
        for (int G = 0; G < 4; ++G)
          acc[G] = __builtin_amdgcn_mfma_f32_16x16x32_bf16(af[ks], bw[G][ks], acc[G], 0, 0, 0);
      __syncthreads();  // A-reads done before h_all is overwritten below
    }

    // gates, directly in C-layout: lane owns (jj, batches 4q..4q+3)
    float hn[4];
    #pragma unroll
    for (int r = 0; r < 4; ++r) {
      float z0 = acc[0][r] + b0 + xp[0][r];
      float z1 = acc[1][r] + b1 + xp[1][r];
      float z2 = acc[2][r] + b2 + xp[2][r];
      float z3 = acc[3][r] + b3 + xp[3][r];
      float ig = sigm(z0 + c2[r] * pci);
      float fg = sigm(z1 + c2[r] * pcf);
      float cn = fg * c2[r] + ig * tanh_(z2);
      float og = sigm(z3 + cn * pco);
      float h = og * tanh_(cn);
      c2[r] = cn;
      hn[r] = h;
      if ((r & 1) && s < 511) {  // publish pair ASAP: overlaps remaining gates
        unsigned long long pv =
            ((unsigned long long)(unsigned)(s + 1) << 32) |
            (unsigned long long)(((uint32_t)f2bf(hn[r - 1])) |
                                 ((uint32_t)f2bf(hn[r]) << 16));
        __hip_atomic_store(mypub + (size_t)((s + 1) & 1) * 16384 + (r >> 1), pv,
                           __ATOMIC_RELAXED, __HIP_MEMORY_SCOPE_AGENT);
      }
    }
    #pragma unroll
    for (int r = 0; r < 4; ++r) h_all[4 * q + r][jg] = f2bf(hn[r]);
    // y = tanh(BN(h)) -> xw col jg (consumed via prefetch; final FC reads later)
    #pragma unroll
    for (int r = 0; r < 4; ++r) {
      float y = tanh_(hn[r] * bna + bnb);
      xw[((xbase + ((size_t)r << 9) + s) << 10) + jg] = __float2half(y);
    }
    // prefetch xw for s+1 (latency hidden under next poll/MFMA)
    if (s < 511) {
      #pragma unroll
      for (int G = 0; G < 4; ++G)
        #pragma unroll
        for (int r = 0; r < 4; ++r)
          xp[G][r] = __half2float(
              xw[((xbase + ((size_t)r << 9) + (s + 1)) << 10) + G * 256 + jg]);
    }
  }
}

// ---- final FC: out[b,t,c] = sum_j y[b,t,j] * fcw[j,c]; wave per row ----
__global__ __launch_bounds__(256) void final_fc(const __half* __restrict__ xw,
                                                const float* __restrict__ fcw,
                                                float* __restrict__ out) {
  const int tid = threadIdx.x, lane = tid & 63, w = tid >> 6;
  const int wid = blockIdx.x * 4 + w;  // 512 waves
  float fw[4][10];
  #pragma unroll
  for (int q = 0; q < 4; ++q)
    #pragma unroll
    for (int c = 0; c < 10; ++c) fw[q][c] = fcw[(lane * 4 + q) * 10 + c];
  for (int it = 0; it < 128; ++it) {
    const int row = it * 512 + wid;
    uint2 u = *(const uint2*)(xw + ((size_t)row << 10) + lane * 4);
    const __half* hp = (const __half*)&u;
    float y0 = __half2float(hp[0]), y1 = __half2float(hp[1]);
    float y2 = __half2float(hp[2]), y3 = __half2float(hp[3]);
    float p[10];
    #pragma unroll
    for (int c = 0; c < 10; ++c)
      p[c] = y0 * fw[0][c] + y1 * fw[1][c] + y2 * fw[2][c] + y3 * fw[3][c];
    #pragma unroll
    for (int off = 1; off < 64; off <<= 1)
      #pragma unroll
      for (int c = 0; c < 10; ++c) p[c] += __shfl_xor(p[c], off, 64);
    if (lane == 0) {
      #pragma unroll
      for (int c = 0; c < 10; ++c) out[(size_t)row * 10 + c] = p[c];
    }
  }
}

extern "C" void kernel_launch(void* const* d_in, const int* in_sizes, int n_in,
                              void* d_out, int out_size, void* d_ws, size_t ws_size,
                              hipStream_t stream) {
  const float* x     = (const float*)d_in[0];
  const float* kw    = (const float*)d_in[1];
  const float* rk    = (const float*)d_in[2];
  const float* bias  = (const float*)d_in[3];
  const float* wci   = (const float*)d_in[4];
  const float* wcf   = (const float*)d_in[5];
  const float* wco   = (const float*)d_in[6];
  const float* gamma = (const float*)d_in[7];
  const float* beta  = (const float*)d_in[8];
  const float* mean  = (const float*)d_in[9];
  const float* var   = (const float*)d_in[10];
  const float* fcw   = (const float*)d_in[11];
  float* out = (float*)d_out;

  char* ws = (char*)d_ws;
  __half*         xw    = (__half*)ws;                                 // 134217728 B
  unsigned short* wt_hi = (unsigned short*)(ws + 134217728);           // 1638400 B
  unsigned short* wt_lo = (unsigned short*)(ws + 134217728 + 1638400); // 1638400 B
  unsigned short* wfrag = (unsigned short*)(ws + 134217728 + 3276800); // 524288 B
  // pub overlays wt_hi (dead after gemm_xw): 2 parity * 32 WG * 512 u64 = 262144 B
  unsigned long long* pub = (unsigned long long*)(ws + 134217728);

  repack_w<<<dim3((1024 * 800 + 255) / 256), dim3(256), 0, stream>>>(kw, wt_hi, wt_lo);
  repack_wf<<<dim3(128), dim3(256), 0, stream>>>(rk, wfrag);
  gemm_xw<<<dim3(8, 512), dim3(256), 0, stream>>>(x, wt_hi, wt_lo, xw);
  scan_kernel<<<dim3(32), dim3(256), 0, stream>>>(wfrag, xw, pub, bias,
                                                  wci, wcf, wco, gamma, beta, mean, var);
  final_fc<<<dim3(128), dim3(256), 0, stream>>>(xw, fcw, out);
}